// Round 5
// baseline (342.004 us; speedup 1.0000x reference)
//
#include <hip/hip_runtime.h>

typedef unsigned short ushort_t;
typedef __bf16 bf16x8 __attribute__((ext_vector_type(8)));
typedef float f32x4 __attribute__((ext_vector_type(4)));

__device__ __forceinline__ unsigned short f2bf(float f) {
    unsigned u = __float_as_uint(f);
    u += 0x7fffu + ((u >> 16) & 1u);
    return (unsigned short)(u >> 16);
}
__device__ __forceinline__ float bf2f(unsigned short h) {
    return __uint_as_float(((unsigned)h) << 16);
}
__device__ __forceinline__ float gelu_f(float x) {
    return 0.5f * x * (1.0f + erff(x * 0.70710678118654752440f));
}

// ---------------- prep: convert X -> bf16 AND transpose both weights ----------------
// (round-0 verified form)
// blocks [0,16384): X rows; [16384,18432): W_down transpose; [18432,19456): W_row transpose
__global__ void prep_kernel(const float4* __restrict__ former,
                            const float4* __restrict__ hidden,
                            uint4* __restrict__ Xb4,
                            const float* __restrict__ Wd, ushort_t* __restrict__ WdT,
                            const float* __restrict__ Wr, ushort_t* __restrict__ WrT)
{
    const int blk = blockIdx.x;
    const int tid = threadIdx.x;
    if (blk < 16384) {
        // one X row per block: cols 0-1023 from former, 1024-2047 from hidden
        const int row = blk;
        const float4* src = (tid < 128)
            ? (former + (size_t)row * 256 + (tid & 127) * 2)
            : (hidden + (size_t)row * 256 + (tid & 127) * 2);
        float4 a = src[0], b = src[1];
        uint4 o;
        o.x = f2bf(a.x) | ((unsigned)f2bf(a.y) << 16);
        o.y = f2bf(a.z) | ((unsigned)f2bf(a.w) << 16);
        o.z = f2bf(b.x) | ((unsigned)f2bf(b.y) << 16);
        o.w = f2bf(b.z) | ((unsigned)f2bf(b.w) << 16);
        Xb4[(size_t)row * 256 + tid] = o;
    } else {
        // tiled transpose f32 [R][C] -> bf16 [C][R]
        __shared__ float tile[32][33];
        const float* W; ushort_t* Wt; int R, C, b;
        if (blk < 16384 + 2048) { b = blk - 16384; W = Wd; Wt = WdT; R = 2048; C = 1024; }
        else                    { b = blk - 18432; W = Wr; Wt = WrT; R = 1024; C = 1024; }
        const int bx = (b & 31) * 32;
        const int by = (b >> 5) * 32;
        const int tx = tid & 31, ty = tid >> 5;
        #pragma unroll
        for (int j = 0; j < 32; j += 8)
            tile[ty + j][tx] = W[(size_t)(by + ty + j) * C + bx + tx];
        __syncthreads();
        #pragma unroll
        for (int j = 0; j < 32; j += 8)
            Wt[(size_t)(bx + ty + j) * R + by + tx] = f2bf(tile[tx][ty + j]);
    }
}

// ---------------- 128^2 m97-style bf16 GEMM (round-0 verified, 81.8 us as GEMM1) -------
// A: [M][K] bf16 row-major, Bt: [N][K] bf16 row-major, C: [M][N] bf16
__global__ void gemm_bias_gelu_kernel(const ushort_t* __restrict__ A,
                                      const ushort_t* __restrict__ Bt,
                                      const float* __restrict__ bias,
                                      ushort_t* __restrict__ C,
                                      int M, int N, int K)
{
    __shared__ __align__(16) ushort_t sA[128 * 64];
    __shared__ __align__(16) ushort_t sB[128 * 64];
    const int tid  = threadIdx.x;
    const int lane = tid & 63;
    const int wave = tid >> 6;
    const int wm = (wave & 1) * 64;
    const int wn = (wave >> 1) * 64;
    const long bm = (long)blockIdx.x * 128;
    const long bn = (long)blockIdx.y * 128;

    f32x4 acc[4][4] = {};

    const int srow = wave * 8 + (lane >> 3);
    const int scol = ((lane & 7) ^ (lane >> 3)) * 8;
    const int ldsbase = wave * 512;

    for (int k0 = 0; k0 < K; k0 += 64) {
        __syncthreads();
        #pragma unroll
        for (int it = 0; it < 4; ++it) {
            const ushort_t* gA = A + (size_t)(bm + it * 32 + srow) * K + k0 + scol;
            const ushort_t* gB = Bt + (size_t)(bn + it * 32 + srow) * K + k0 + scol;
            __builtin_amdgcn_global_load_lds(
                (__attribute__((address_space(1))) void*)gA,
                (__attribute__((address_space(3))) void*)&sA[ldsbase + it * 2048], 16, 0, 0);
            __builtin_amdgcn_global_load_lds(
                (__attribute__((address_space(1))) void*)gB,
                (__attribute__((address_space(3))) void*)&sB[ldsbase + it * 2048], 16, 0, 0);
        }
        __syncthreads();

        const int arow = wm + (lane & 15);
        const int brow = wn + (lane & 15);
        const int sw = lane & 7;
        const int cbase = lane >> 4;
        #pragma unroll
        for (int kk = 0; kk < 64; kk += 32) {
            const int koff = (((kk >> 3) + cbase) ^ sw) << 3;
            bf16x8 af[4], bfr[4];
            #pragma unroll
            for (int t = 0; t < 4; ++t) {
                af[t]  = *(const bf16x8*)&sA[(arow + t * 16) * 64 + koff];
                bfr[t] = *(const bf16x8*)&sB[(brow + t * 16) * 64 + koff];
            }
            #pragma unroll
            for (int i = 0; i < 4; ++i)
                #pragma unroll
                for (int j = 0; j < 4; ++j)
                    acc[i][j] = __builtin_amdgcn_mfma_f32_16x16x32_bf16(af[i], bfr[j], acc[i][j], 0, 0, 0);
        }
    }

    // epilogue: C/D layout col=lane&15, row=(lane>>4)*4+reg   [m89/m91 verified]
    #pragma unroll
    for (int i = 0; i < 4; ++i) {
        const long row0 = bm + wm + i * 16 + (lane >> 4) * 4;
        #pragma unroll
        for (int j = 0; j < 4; ++j) {
            const long col = bn + wn + j * 16 + (lane & 15);
            const float bv = bias[col];
            #pragma unroll
            for (int r = 0; r < 4; ++r) {
                float v = gelu_f(acc[i][j][r] + bv);
                C[(size_t)(row0 + r) * N + col] = f2bf(v);
            }
        }
    }
}

// ---------------- segment sum + CSR emit ----------------------------------------------
// cell[b,t,:] = sum_{l: ids[b,l]==t} seq[b,l,:]; also writes counts[m] and the token
// list (ushort) per cell m=b*256+t so gemm2 can scatter directly to out (gather fused).
__global__ void segsum_kernel(const ushort_t* __restrict__ seq,   // [8*2048][1024] bf16
                              const int* __restrict__ ids,        // [8][2048]
                              ushort_t* __restrict__ cell,        // [8*256][1024] bf16
                              int* __restrict__ counts,           // [2048]
                              ushort_t* __restrict__ lists)       // [2048][2048]
{
    const int b = blockIdx.x >> 8;
    const int t = blockIdx.x & 255;
    const int m = blockIdx.x;
    __shared__ int list[2048];
    __shared__ int count;
    if (threadIdx.x == 0) count = 0;
    __syncthreads();
    const int* idrow = ids + b * 2048;
    for (int l = threadIdx.x; l < 2048; l += 256) {
        if (idrow[l] == t) list[atomicAdd(&count, 1)] = l;
    }
    __syncthreads();
    const int n = count;
    // CSR emit
    if (threadIdx.x == 0) counts[m] = n;
    for (int i = threadIdx.x; i < n; i += 256)
        lists[(size_t)m * 2048 + i] = (ushort_t)list[i];
    // unroll-2 accumulation: pair of independent row loads per iter hides latency
    float a0 = 0.f, a1 = 0.f, a2 = 0.f, a3 = 0.f;
    int i = 0;
    for (; i + 1 < n; i += 2) {
        const int l0 = list[i], l1 = list[i + 1];
        const ushort4 v0 = *(const ushort4*)(seq + (size_t)(b * 2048 + l0) * 1024 + threadIdx.x * 4);
        const ushort4 v1 = *(const ushort4*)(seq + (size_t)(b * 2048 + l1) * 1024 + threadIdx.x * 4);
        a0 += bf2f(v0.x) + bf2f(v1.x);
        a1 += bf2f(v0.y) + bf2f(v1.y);
        a2 += bf2f(v0.z) + bf2f(v1.z);
        a3 += bf2f(v0.w) + bf2f(v1.w);
    }
    if (i < n) {
        const int l0 = list[i];
        const ushort4 v0 = *(const ushort4*)(seq + (size_t)(b * 2048 + l0) * 1024 + threadIdx.x * 4);
        a0 += bf2f(v0.x); a1 += bf2f(v0.y); a2 += bf2f(v0.z); a3 += bf2f(v0.w);
    }
    ushort4* out = (ushort4*)(cell + (size_t)m * 1024);
    out[threadIdx.x] = make_ushort4(f2bf(a0), f2bf(a1), f2bf(a2), f2bf(a3));
}

// ---------------- GEMM2 + fused gather scatter ----------------------------------------
// cello[m,:] = gelu(cellb[m,:] @ WrT^T + bias); out[b,l,:] = cello[b,ids[b,l],:]
// Instead of materializing cello + a gather pass, the epilogue scatters each computed
// cell row to every token row in its CSR list. No write conflicts: each (m, col) is
// owned by exactly one block/lane, and each l belongs to exactly one m.
__global__ void gemm2_scatter_kernel(const ushort_t* __restrict__ A,   // cellb [2048][1024]
                                     const ushort_t* __restrict__ Bt,  // WrT [1024][1024]
                                     const float* __restrict__ bias,
                                     const int* __restrict__ counts,   // [2048]
                                     const ushort_t* __restrict__ lists,// [2048][2048]
                                     float* __restrict__ out)          // [8*2048][1024] f32
{
    const int N = 1024, K = 1024;
    __shared__ __align__(16) ushort_t sA[128 * 64];
    __shared__ __align__(16) ushort_t sB[128 * 64];
    const int tid  = threadIdx.x;
    const int lane = tid & 63;
    const int wave = tid >> 6;
    const int wm = (wave & 1) * 64;
    const int wn = (wave >> 1) * 64;
    const long bm = (long)blockIdx.x * 128;
    const long bn = (long)blockIdx.y * 128;

    f32x4 acc[4][4] = {};

    const int srow = wave * 8 + (lane >> 3);
    const int scol = ((lane & 7) ^ (lane >> 3)) * 8;
    const int ldsbase = wave * 512;

    for (int k0 = 0; k0 < K; k0 += 64) {
        __syncthreads();
        #pragma unroll
        for (int it = 0; it < 4; ++it) {
            const ushort_t* gA = A + (size_t)(bm + it * 32 + srow) * K + k0 + scol;
            const ushort_t* gB = Bt + (size_t)(bn + it * 32 + srow) * K + k0 + scol;
            __builtin_amdgcn_global_load_lds(
                (__attribute__((address_space(1))) void*)gA,
                (__attribute__((address_space(3))) void*)&sA[ldsbase + it * 2048], 16, 0, 0);
            __builtin_amdgcn_global_load_lds(
                (__attribute__((address_space(1))) void*)gB,
                (__attribute__((address_space(3))) void*)&sB[ldsbase + it * 2048], 16, 0, 0);
        }
        __syncthreads();

        const int arow = wm + (lane & 15);
        const int brow = wn + (lane & 15);
        const int sw = lane & 7;
        const int cbase = lane >> 4;
        #pragma unroll
        for (int kk = 0; kk < 64; kk += 32) {
            const int koff = (((kk >> 3) + cbase) ^ sw) << 3;
            bf16x8 af[4], bfr[4];
            #pragma unroll
            for (int t = 0; t < 4; ++t) {
                af[t]  = *(const bf16x8*)&sA[(arow + t * 16) * 64 + koff];
                bfr[t] = *(const bf16x8*)&sB[(brow + t * 16) * 64 + koff];
            }
            #pragma unroll
            for (int i = 0; i < 4; ++i)
                #pragma unroll
                for (int j = 0; j < 4; ++j)
                    acc[i][j] = __builtin_amdgcn_mfma_f32_16x16x32_bf16(af[i], bfr[j], acc[i][j], 0, 0, 0);
        }
    }

    // epilogue: per output row m, scatter gelu(row) to all token rows in its list.
    const long colb[4] = { bn + wn + 0 * 16 + (lane & 15), bn + wn + 1 * 16 + (lane & 15),
                           bn + wn + 2 * 16 + (lane & 15), bn + wn + 3 * 16 + (lane & 15) };
    float bv[4];
    #pragma unroll
    for (int j = 0; j < 4; ++j) bv[j] = bias[colb[j]];

    #pragma unroll
    for (int i = 0; i < 4; ++i) {
        const long row0 = bm + wm + i * 16 + (lane >> 4) * 4;
        #pragma unroll
        for (int r = 0; r < 4; ++r) {
            const int m = (int)(row0 + r);          // cell index: b*256 + t
            const int b = m >> 8;
            const int n_ = counts[m];
            const ushort_t* lp = lists + (size_t)m * 2048;
            float v[4];
            #pragma unroll
            for (int j = 0; j < 4; ++j) v[j] = gelu_f(acc[i][j][r] + bv[j]);
            for (int e = 0; e < n_; ++e) {
                const int l = lp[e];
                float* op = out + ((size_t)(b * 2048 + l)) * 1024;
                #pragma unroll
                for (int j = 0; j < 4; ++j) op[colb[j]] = v[j];
            }
        }
    }
}

extern "C" void kernel_launch(void* const* d_in, const int* in_sizes, int n_in,
                              void* d_out, int out_size, void* d_ws, size_t ws_size,
                              hipStream_t stream) {
    const float* former = (const float*)d_in[0];   // [8,2048,1024] f32
    const float* hidden = (const float*)d_in[1];   // [8,2048,1024] f32
    const int*   ids    = (const int*)d_in[2];     // [8,2048] i32
    // d_in[3] attention_mask: unused by reference
    const float* W_down = (const float*)d_in[4];   // [2048,1024] f32
    const float* b_down = (const float*)d_in[5];   // [1024] f32
    const float* W_row  = (const float*)d_in[6];   // [1024,1024] f32
    const float* b_row  = (const float*)d_in[7];   // [1024] f32
    float* out = (float*)d_out;                    // [8,2048,1024] f32

    char* ws = (char*)d_ws;
    ushort_t* Xb     = (ushort_t*)ws;  ws += (size_t)16384 * 2048 * 2;  // 64 MiB
    ushort_t* WdT    = (ushort_t*)ws;  ws += (size_t)1024 * 2048 * 2;   //  4 MiB
    ushort_t* WrT    = (ushort_t*)ws;  ws += (size_t)1024 * 1024 * 2;   //  2 MiB
    ushort_t* seq    = (ushort_t*)ws;  ws += (size_t)16384 * 1024 * 2;  // 32 MiB
    ushort_t* cellb  = (ushort_t*)ws;  ws += (size_t)2048 * 1024 * 2;   //  4 MiB
    int*      counts = (int*)ws;       ws += (size_t)2048 * 4;          //  8 KiB
    ushort_t* lists  = (ushort_t*)ws;                                   //  8 MiB

    prep_kernel<<<19456, 256, 0, stream>>>((const float4*)former, (const float4*)hidden,
                                           (uint4*)Xb, W_down, WdT, W_row, WrT);

    // GEMM1: [16384 x 2048] @ [2048 x 1024] -> gelu -> bf16 seq (round-0 verified form)
    gemm_bias_gelu_kernel<<<dim3(128, 8), 256, 0, stream>>>(Xb, WdT, b_down, seq,
                                                            16384, 1024, 2048);

    segsum_kernel<<<2048, 256, 0, stream>>>(seq, ids, cellb, counts, lists);

    // GEMM2 + fused gather: [2048 x 1024] @ [1024 x 1024] -> gelu -> scatter to out
    gemm2_scatter_kernel<<<dim3(16, 8), 256, 0, stream>>>(cellb, WrT, b_row,
                                                          counts, lists, out);
}

// Round 6
// 323.376 us; speedup vs baseline: 1.0576x; 1.0576x over previous
//
#include <hip/hip_runtime.h>

typedef unsigned short ushort_t;
typedef __bf16 bf16x8 __attribute__((ext_vector_type(8)));
typedef float f32x4 __attribute__((ext_vector_type(4)));

__device__ __forceinline__ unsigned short f2bf(float f) {
    unsigned u = __float_as_uint(f);
    u += 0x7fffu + ((u >> 16) & 1u);
    return (unsigned short)(u >> 16);
}
__device__ __forceinline__ float bf2f(unsigned short h) {
    return __uint_as_float(((unsigned)h) << 16);
}
__device__ __forceinline__ float gelu_f(float x) {
    return 0.5f * x * (1.0f + erff(x * 0.70710678118654752440f));
}

// ---------------- prep: convert X -> bf16 (grid-stride, ILP=8) + transpose weights -----
// blocks [0,2048): X flat grid-stride; [2048,4096): W_down transpose; [4096,5120): W_row.
// X: unit u = one output uint4 (8 bf16). row = u>>8, q = u&255; q<128 reads former
// float4 pair (q*2, q*2+1), else hidden ((q-128)*2). Output index == u (coalesced).
__global__ void prep_kernel(const float4* __restrict__ former,
                            const float4* __restrict__ hidden,
                            uint4* __restrict__ Xb4,
                            const float* __restrict__ Wd, ushort_t* __restrict__ WdT,
                            const float* __restrict__ Wr, ushort_t* __restrict__ WrT)
{
    const int blk = blockIdx.x;
    const int tid = threadIdx.x;
    if (blk < 2048) {
        // 16384 rows x 256 uint4 = 4,194,304 units; 524,288 threads -> 8 units each
        int u = blk * 256 + tid;
        const int stride = 2048 * 256;
        #pragma unroll
        for (int it = 0; it < 8; ++it, u += stride) {
            const int row = u >> 8;
            const int q = u & 255;
            const float4* src = (q < 128)
                ? (former + (size_t)row * 256 + q * 2)
                : (hidden + (size_t)row * 256 + (q - 128) * 2);
            float4 a = src[0], b = src[1];
            uint4 o;
            o.x = f2bf(a.x) | ((unsigned)f2bf(a.y) << 16);
            o.y = f2bf(a.z) | ((unsigned)f2bf(a.w) << 16);
            o.z = f2bf(b.x) | ((unsigned)f2bf(b.y) << 16);
            o.w = f2bf(b.z) | ((unsigned)f2bf(b.w) << 16);
            Xb4[u] = o;
        }
    } else {
        // tiled transpose f32 [R][C] -> bf16 [C][R]  (round-0 verified form)
        __shared__ float tile[32][33];
        const float* W; ushort_t* Wt; int R, C, b;
        const int b2 = blk - 2048;
        if (b2 < 2048) { b = b2;        W = Wd; Wt = WdT; R = 2048; C = 1024; }
        else           { b = b2 - 2048; W = Wr; Wt = WrT; R = 1024; C = 1024; }
        const int bx = (b & 31) * 32;
        const int by = (b >> 5) * 32;
        const int tx = tid & 31, ty = tid >> 5;
        #pragma unroll
        for (int j = 0; j < 32; j += 8)
            tile[ty + j][tx] = W[(size_t)(by + ty + j) * C + bx + tx];
        __syncthreads();
        #pragma unroll
        for (int j = 0; j < 32; j += 8)
            Wt[(size_t)(bx + ty + j) * R + by + tx] = f2bf(tile[tx][ty + j]);
    }
}

// ---------------- 128^2 m97-style bf16 GEMM (round-0 verified) -------------------------
// A: [M][K] bf16 row-major, Bt: [N][K] bf16 row-major, C: [M][N] (bf16 or f32)
template <bool OUT_BF16>
__global__ void gemm_bias_gelu_kernel(const ushort_t* __restrict__ A,
                                      const ushort_t* __restrict__ Bt,
                                      const float* __restrict__ bias,
                                      void* __restrict__ C,
                                      int M, int N, int K)
{
    __shared__ __align__(16) ushort_t sA[128 * 64];
    __shared__ __align__(16) ushort_t sB[128 * 64];
    const int tid  = threadIdx.x;
    const int lane = tid & 63;
    const int wave = tid >> 6;
    const int wm = (wave & 1) * 64;
    const int wn = (wave >> 1) * 64;
    const long bm = (long)blockIdx.x * 128;
    const long bn = (long)blockIdx.y * 128;

    f32x4 acc[4][4] = {};

    const int srow = wave * 8 + (lane >> 3);
    const int scol = ((lane & 7) ^ (lane >> 3)) * 8;
    const int ldsbase = wave * 512;

    for (int k0 = 0; k0 < K; k0 += 64) {
        __syncthreads();
        #pragma unroll
        for (int it = 0; it < 4; ++it) {
            const ushort_t* gA = A + (size_t)(bm + it * 32 + srow) * K + k0 + scol;
            const ushort_t* gB = Bt + (size_t)(bn + it * 32 + srow) * K + k0 + scol;
            __builtin_amdgcn_global_load_lds(
                (__attribute__((address_space(1))) void*)gA,
                (__attribute__((address_space(3))) void*)&sA[ldsbase + it * 2048], 16, 0, 0);
            __builtin_amdgcn_global_load_lds(
                (__attribute__((address_space(1))) void*)gB,
                (__attribute__((address_space(3))) void*)&sB[ldsbase + it * 2048], 16, 0, 0);
        }
        __syncthreads();

        const int arow = wm + (lane & 15);
        const int brow = wn + (lane & 15);
        const int sw = lane & 7;
        const int cbase = lane >> 4;
        #pragma unroll
        for (int kk = 0; kk < 64; kk += 32) {
            const int koff = (((kk >> 3) + cbase) ^ sw) << 3;
            bf16x8 af[4], bfr[4];
            #pragma unroll
            for (int t = 0; t < 4; ++t) {
                af[t]  = *(const bf16x8*)&sA[(arow + t * 16) * 64 + koff];
                bfr[t] = *(const bf16x8*)&sB[(brow + t * 16) * 64 + koff];
            }
            #pragma unroll
            for (int i = 0; i < 4; ++i)
                #pragma unroll
                for (int j = 0; j < 4; ++j)
                    acc[i][j] = __builtin_amdgcn_mfma_f32_16x16x32_bf16(af[i], bfr[j], acc[i][j], 0, 0, 0);
        }
    }

    // epilogue: C/D layout col=lane&15, row=(lane>>4)*4+reg   [m89/m91 verified]
    #pragma unroll
    for (int i = 0; i < 4; ++i) {
        const long row0 = bm + wm + i * 16 + (lane >> 4) * 4;
        #pragma unroll
        for (int j = 0; j < 4; ++j) {
            const long col = bn + wn + j * 16 + (lane & 15);
            const float bv = bias[col];
            #pragma unroll
            for (int r = 0; r < 4; ++r) {
                float v = gelu_f(acc[i][j][r] + bv);
                if (OUT_BF16)
                    ((ushort_t*)C)[(size_t)(row0 + r) * N + col] = f2bf(v);
                else
                    ((float*)C)[(size_t)(row0 + r) * N + col] = v;
            }
        }
    }
}

// ---------------- segment sum: cell[b,t,:] = sum_{l: ids[b,l]==t} seq[b,l,:] -----------
// unroll-2 accumulation: two independent row loads in flight per iteration.
__global__ void segsum_kernel(const ushort_t* __restrict__ seq,   // [8*2048][1024] bf16
                              const int* __restrict__ ids,        // [8][2048]
                              ushort_t* __restrict__ cell)        // [8*256][1024] bf16
{
    const int b = blockIdx.x >> 8;
    const int t = blockIdx.x & 255;
    __shared__ int list[2048];
    __shared__ int count;
    if (threadIdx.x == 0) count = 0;
    __syncthreads();
    const int* idrow = ids + b * 2048;
    for (int l = threadIdx.x; l < 2048; l += 256) {
        if (idrow[l] == t) list[atomicAdd(&count, 1)] = l;
    }
    __syncthreads();
    const int n = count;
    float a0 = 0.f, a1 = 0.f, a2 = 0.f, a3 = 0.f;
    int i = 0;
    for (; i + 1 < n; i += 2) {
        const int l0 = list[i], l1 = list[i + 1];
        const ushort4 v0 = *(const ushort4*)(seq + (size_t)(b * 2048 + l0) * 1024 + threadIdx.x * 4);
        const ushort4 v1 = *(const ushort4*)(seq + (size_t)(b * 2048 + l1) * 1024 + threadIdx.x * 4);
        a0 += bf2f(v0.x) + bf2f(v1.x);
        a1 += bf2f(v0.y) + bf2f(v1.y);
        a2 += bf2f(v0.z) + bf2f(v1.z);
        a3 += bf2f(v0.w) + bf2f(v1.w);
    }
    if (i < n) {
        const int l0 = list[i];
        const ushort4 v0 = *(const ushort4*)(seq + (size_t)(b * 2048 + l0) * 1024 + threadIdx.x * 4);
        a0 += bf2f(v0.x); a1 += bf2f(v0.y); a2 += bf2f(v0.z); a3 += bf2f(v0.w);
    }
    ushort4* out = (ushort4*)(cell + (size_t)(b * 256 + t) * 1024);
    out[threadIdx.x] = make_ushort4(f2bf(a0), f2bf(a1), f2bf(a2), f2bf(a3));
}

// ---------------- gather: out[b,l,:] = cellout[b, ids[b,l], :]  (ILP=4) ----------------
// 4 tokens per block: 4 independent float4 load/store pairs per thread. 4-token groups
// never straddle a batch boundary (2048 % 4 == 0).
__global__ void gather_kernel(const float4* __restrict__ cellout,  // [8*256][256] float4
                              const int* __restrict__ ids,
                              float4* __restrict__ out)            // [8*2048][256] float4
{
    const int base = blockIdx.x * 4;       // first token: b*2048 + l
    const int b = base >> 11;
    const int tid = threadIdx.x;
    const int t0 = ids[base + 0];
    const int t1 = ids[base + 1];
    const int t2 = ids[base + 2];
    const int t3 = ids[base + 3];
    const float4 v0 = cellout[(size_t)(b * 256 + t0) * 256 + tid];
    const float4 v1 = cellout[(size_t)(b * 256 + t1) * 256 + tid];
    const float4 v2 = cellout[(size_t)(b * 256 + t2) * 256 + tid];
    const float4 v3 = cellout[(size_t)(b * 256 + t3) * 256 + tid];
    out[(size_t)(base + 0) * 256 + tid] = v0;
    out[(size_t)(base + 1) * 256 + tid] = v1;
    out[(size_t)(base + 2) * 256 + tid] = v2;
    out[(size_t)(base + 3) * 256 + tid] = v3;
}

extern "C" void kernel_launch(void* const* d_in, const int* in_sizes, int n_in,
                              void* d_out, int out_size, void* d_ws, size_t ws_size,
                              hipStream_t stream) {
    const float* former = (const float*)d_in[0];   // [8,2048,1024] f32
    const float* hidden = (const float*)d_in[1];   // [8,2048,1024] f32
    const int*   ids    = (const int*)d_in[2];     // [8,2048] i32
    // d_in[3] attention_mask: unused by reference
    const float* W_down = (const float*)d_in[4];   // [2048,1024] f32
    const float* b_down = (const float*)d_in[5];   // [1024] f32
    const float* W_row  = (const float*)d_in[6];   // [1024,1024] f32
    const float* b_row  = (const float*)d_in[7];   // [1024] f32
    float* out = (float*)d_out;                    // [8,2048,1024] f32

    char* ws = (char*)d_ws;
    ushort_t* Xb    = (ushort_t*)ws;  ws += (size_t)16384 * 2048 * 2;  // 64 MiB
    ushort_t* WdT   = (ushort_t*)ws;  ws += (size_t)1024 * 2048 * 2;   //  4 MiB
    ushort_t* WrT   = (ushort_t*)ws;  ws += (size_t)1024 * 1024 * 2;   //  2 MiB
    ushort_t* seq   = (ushort_t*)ws;  ws += (size_t)16384 * 1024 * 2;  // 32 MiB
    ushort_t* cellb = (ushort_t*)ws;  ws += (size_t)2048 * 1024 * 2;   //  4 MiB
    float*    cello = (float*)ws;                                      //  8 MiB

    prep_kernel<<<5120, 256, 0, stream>>>((const float4*)former, (const float4*)hidden,
                                          (uint4*)Xb, W_down, WdT, W_row, WrT);

    // GEMM1: [16384 x 2048] @ [2048 x 1024] -> gelu -> bf16 seq (round-0 verified form)
    gemm_bias_gelu_kernel<true><<<dim3(128, 8), 256, 0, stream>>>(Xb, WdT, b_down, seq,
                                                                  16384, 1024, 2048);

    segsum_kernel<<<2048, 256, 0, stream>>>(seq, ids, cellb);

    // GEMM2: [2048 x 1024] @ [1024 x 1024] -> gelu -> f32 cello
    gemm_bias_gelu_kernel<false><<<dim3(16, 8), 256, 0, stream>>>(cellb, WrT, b_row, cello,
                                                                  2048, 1024, 1024);

    gather_kernel<<<4096, 256, 0, stream>>>((const float4*)cello, ids, (float4*)out);
}